// Round 4
// baseline (645.991 us; speedup 1.0000x reference)
//
#include <hip/hip_runtime.h>

// GumbelCodebook: y = one_hot(argmax(logits+gumbel)), z = codebook[argmax]
// Shapes: logits/gumbel [8,4096,2048] f32, codebook [2048,256] f32
// Outputs concatenated in d_out: z [8,4096,256] then y [8,4096,2048], f32.
//
// v4: fused single kernel (no memset phase), all output stores non-temporal.
//  - Empirics from v1-v3: reads cap at ~3.2 TB/s (= copy ubench read
//    component); writes hit 6.3 TB/s at 10% occupancy (fills). So the floor
//    is the 512MB read stream (~160us) with writes hidden beneath it. The
//    split design serialized 45us of pure-write memset; fuse instead.
//  - NT stores for y and z: 288MB of output never re-read -> bypass L2/L3
//    allocation, preserving cache capacity for the input streams (round-0
//    showed 46% L3 read-hit; write-allocate pollution erodes it).
//  - One wave per token (64 lanes x 32 codes), butterfly argmax, no LDS,
//    no __syncthreads. Grid-stride, 2048 persistent blocks.

#define NUM_CODES 2048
#define CODE_DIM  256
#define BLOCK     256
#define WAVES_PER_BLOCK (BLOCK / 64)

typedef float vfloat4 __attribute__((ext_vector_type(4)));

__device__ __forceinline__ void upd(vfloat4 l, vfloat4 g, int base,
                                    float& best, int& bestIdx) {
    float s0 = l.x + g.x;
    float s1 = l.y + g.y;
    float s2 = l.z + g.z;
    float s3 = l.w + g.w;
    if (s0 > best) { best = s0; bestIdx = base + 0; }
    if (s1 > best) { best = s1; bestIdx = base + 1; }
    if (s2 > best) { best = s2; bestIdx = base + 2; }
    if (s3 > best) { best = s3; bestIdx = base + 3; }
}

__global__ __launch_bounds__(BLOCK, 8) void gumbel_codebook_kernel(
    const float* __restrict__ logits,
    const float* __restrict__ gumbel,
    const float* __restrict__ codebook,
    float* __restrict__ z_out,   // [tokens, CODE_DIM]
    float* __restrict__ y_out,   // [tokens, NUM_CODES]
    int tokens)
{
    const int lane = threadIdx.x & 63;
    const int wave = threadIdx.x >> 6;
    const int stride = gridDim.x * WAVES_PER_BLOCK;

    for (int token = blockIdx.x * WAVES_PER_BLOCK + wave; token < tokens;
         token += stride) {
        const size_t row_off = (size_t)token * NUM_CODES;
        const vfloat4* lrow = (const vfloat4*)(logits + row_off);
        const vfloat4* grow = (const vfloat4*)(gumbel + row_off);

        // --- per-lane argmax over 32 codes, batches of 4 vec-pairs so 8
        // float4 loads are in flight per batch. For fixed lane the index
        // (c*64+lane)*4 increases with c, so strict '>' keeps the first
        // (lowest-index) max within the lane — matching jnp.argmax. ---
        float best = -INFINITY;
        int bestIdx = NUM_CODES;  // sentinel
#pragma unroll
        for (int h = 0; h < 2; ++h) {
            const int c0 = h * 4;
            vfloat4 l0 = lrow[(c0 + 0) * 64 + lane];
            vfloat4 g0 = grow[(c0 + 0) * 64 + lane];
            vfloat4 l1 = lrow[(c0 + 1) * 64 + lane];
            vfloat4 g1 = grow[(c0 + 1) * 64 + lane];
            vfloat4 l2 = lrow[(c0 + 2) * 64 + lane];
            vfloat4 g2 = grow[(c0 + 2) * 64 + lane];
            vfloat4 l3 = lrow[(c0 + 3) * 64 + lane];
            vfloat4 g3 = grow[(c0 + 3) * 64 + lane];
            upd(l0, g0, ((c0 + 0) * 64 + lane) * 4, best, bestIdx);
            upd(l1, g1, ((c0 + 1) * 64 + lane) * 4, best, bestIdx);
            upd(l2, g2, ((c0 + 2) * 64 + lane) * 4, best, bestIdx);
            upd(l3, g3, ((c0 + 3) * 64 + lane) * 4, best, bestIdx);
        }

        // --- wave butterfly argmax; lower index wins ties. ---
#pragma unroll
        for (int m = 1; m < 64; m <<= 1) {
            float ob = __shfl_xor(best, m, 64);
            int   oi = __shfl_xor(bestIdx, m, 64);
            if (ob > best || (ob == best && oi < bestIdx)) {
                best = ob; bestIdx = oi;
            }
        }
        const int amax = bestIdx;

        // --- y one-hot: 8 NT float4 stores per lane (contiguous 8KB/wave,
        // full-line, no L2/L3 allocation). Compare-per-element -> cndmask. ---
        vfloat4* yrow = (vfloat4*)(y_out + row_off);
#pragma unroll
        for (int c = 0; c < 8; ++c) {
            const int vec = c * 64 + lane;
            const int base = vec * 4;
            vfloat4 out;
            out.x = (amax == base + 0) ? 1.0f : 0.0f;
            out.y = (amax == base + 1) ? 1.0f : 0.0f;
            out.z = (amax == base + 2) ? 1.0f : 0.0f;
            out.w = (amax == base + 3) ? 1.0f : 0.0f;
            __builtin_nontemporal_store(out, &yrow[vec]);
        }

        // --- z = codebook[amax]: one float4 per lane. Codebook read is
        // cached (2MB, L2-resident); z store is NT. ---
        const vfloat4* crow =
            (const vfloat4*)(codebook + (size_t)amax * CODE_DIM);
        vfloat4* zrow = (vfloat4*)(z_out + (size_t)token * CODE_DIM);
        vfloat4 zval = crow[lane];
        __builtin_nontemporal_store(zval, &zrow[lane]);
    }
}

extern "C" void kernel_launch(void* const* d_in, const int* in_sizes, int n_in,
                              void* d_out, int out_size, void* d_ws, size_t ws_size,
                              hipStream_t stream) {
    const float* logits   = (const float*)d_in[0];
    const float* gumbel   = (const float*)d_in[1];
    const float* codebook = (const float*)d_in[2];

    const int tokens = in_sizes[0] / NUM_CODES;  // 8*4096 = 32768

    float* z_out = (float*)d_out;                               // [tokens, 256]
    float* y_out = (float*)d_out + (size_t)tokens * CODE_DIM;   // [tokens, 2048]

    int blocks = (tokens + WAVES_PER_BLOCK - 1) / WAVES_PER_BLOCK;
    if (blocks > 2048) blocks = 2048;  // persistent grid-stride
    gumbel_codebook_kernel<<<blocks, BLOCK, 0, stream>>>(
        logits, gumbel, codebook, z_out, y_out, tokens);
}

// Round 5
// 627.717 us; speedup vs baseline: 1.0291x; 1.0291x over previous
//
#include <hip/hip_runtime.h>

// GumbelCodebook: y = one_hot(argmax(logits+gumbel)), z = codebook[argmax]
// Shapes: logits/gumbel [8,4096,2048] f32, codebook [2048,256] f32
// Outputs concatenated in d_out: z [8,4096,256] then y [8,4096,2048], f32.
//
// v5: revert NT stores (v4 regression: FETCH 277->386MB, WRITE 295->412MB)
// and software-pipeline across tokens.
//  - Best-known structure: block-per-token, LDS cross-wave argmax, regular
//    cached stores (round-0: 193us, 3.0 TB/s).
//  - Persistent grid (2048 blocks), grid-stride over tokens, unrolled x2
//    with NAMED register buffers (A/B): token t+1's 8 float4 loads issue
//    BEFORE token t's reduce+stores, so the read stream stays in flight
//    across the vmcnt-drain/barrier/store phase (the compiler emits a
//    partial vmcnt(N) wait for A's regs, leaving B's loads outstanding).
//  - Barriers are block-uniform (token bounds depend only on blockIdx).

#define NUM_CODES 2048
#define CODE_DIM  256
#define BLOCK     256

typedef float vfloat4 __attribute__((ext_vector_type(4)));

__device__ __forceinline__ void upd(vfloat4 l, vfloat4 g, int base,
                                    float& best, int& bestIdx) {
    float s0 = l.x + g.x;
    float s1 = l.y + g.y;
    float s2 = l.z + g.z;
    float s3 = l.w + g.w;
    if (s0 > best) { best = s0; bestIdx = base + 0; }
    if (s1 > best) { best = s1; bestIdx = base + 1; }
    if (s2 > best) { best = s2; bestIdx = base + 2; }
    if (s3 > best) { best = s3; bestIdx = base + 3; }
}

__global__ __launch_bounds__(BLOCK, 8) void gumbel_codebook_kernel(
    const float* __restrict__ logits,
    const float* __restrict__ gumbel,
    const float* __restrict__ codebook,
    float* __restrict__ z_out,   // [tokens, CODE_DIM]
    float* __restrict__ y_out,   // [tokens, NUM_CODES]
    int tokens)
{
    const int tid = threadIdx.x;
    const int stride = gridDim.x;

    __shared__ float s_val[4];
    __shared__ int   s_idx[4];
    __shared__ int   s_amax;
    const int wave = tid >> 6;
    const int lane = tid & 63;

    // ---- load token t's 4 float4 pairs into named regs ----
#define LOADT(L0, G0, L1, G1, t)                                           \
    {                                                                      \
        const vfloat4* lr = (const vfloat4*)(logits + (size_t)(t) * NUM_CODES); \
        const vfloat4* gr = (const vfloat4*)(gumbel + (size_t)(t) * NUM_CODES); \
        L0 = lr[tid];          G0 = gr[tid];                               \
        L1 = lr[BLOCK + tid];  G1 = gr[BLOCK + tid];                       \
    }

    // ---- full per-token pipeline: argmax + y/z stores ----
#define PROCESS(t, L0, G0, L1, G1)                                         \
    {                                                                      \
        float best = -INFINITY;                                            \
        int bestIdx = NUM_CODES;                                           \
        upd(L0, G0, tid * 4, best, bestIdx);                               \
        upd(L1, G1, (BLOCK + tid) * 4, best, bestIdx);                     \
        _Pragma("unroll")                                                  \
        for (int off = 32; off >= 1; off >>= 1) {                          \
            float ob = __shfl_down(best, off, 64);                         \
            int   oi = __shfl_down(bestIdx, off, 64);                      \
            if (ob > best || (ob == best && oi < bestIdx)) {               \
                best = ob; bestIdx = oi;                                   \
            }                                                              \
        }                                                                  \
        if (lane == 0) { s_val[wave] = best; s_idx[wave] = bestIdx; }      \
        __syncthreads();                                                   \
        if (tid == 0) {                                                    \
            float b = s_val[0];                                            \
            int bi = s_idx[0];                                             \
            _Pragma("unroll")                                              \
            for (int w = 1; w < 4; ++w) {                                  \
                float ob = s_val[w];                                       \
                int oi = s_idx[w];                                         \
                if (ob > b || (ob == b && oi < bi)) { b = ob; bi = oi; }   \
            }                                                              \
            s_amax = bi;                                                   \
        }                                                                  \
        __syncthreads();                                                   \
        const int amax = s_amax;                                           \
        const size_t row_off = (size_t)(t) * NUM_CODES;                    \
        vfloat4* yrow = (vfloat4*)(y_out + row_off);                       \
        _Pragma("unroll")                                                  \
        for (int c = 0; c < 2; ++c) {                                      \
            const int vec = c * BLOCK + tid;                               \
            const int base = vec * 4;                                      \
            vfloat4 out;                                                   \
            out.x = (amax == base + 0) ? 1.0f : 0.0f;                      \
            out.y = (amax == base + 1) ? 1.0f : 0.0f;                      \
            out.z = (amax == base + 2) ? 1.0f : 0.0f;                      \
            out.w = (amax == base + 3) ? 1.0f : 0.0f;                      \
            yrow[vec] = out;                                               \
        }                                                                  \
        z_out[(size_t)(t) * CODE_DIM + tid] =                              \
            codebook[(size_t)amax * CODE_DIM + tid];                       \
    }

    int t0 = blockIdx.x;
    if (t0 >= tokens) return;

    vfloat4 La0, Ga0, La1, Ga1;   // buffer A (current token)
    vfloat4 Lb0, Gb0, Lb1, Gb1;   // buffer B (next token)

    LOADT(La0, Ga0, La1, Ga1, t0);
    for (;;) {
        int t1 = t0 + stride;
        if (t1 < tokens) LOADT(Lb0, Gb0, Lb1, Gb1, t1);   // prefetch next
        PROCESS(t0, La0, Ga0, La1, Ga1);
        if (t1 >= tokens) break;

        int t2 = t1 + stride;
        if (t2 < tokens) LOADT(La0, Ga0, La1, Ga1, t2);   // prefetch next
        PROCESS(t1, Lb0, Gb0, Lb1, Gb1);
        if (t2 >= tokens) break;

        t0 = t2;
    }
#undef LOADT
#undef PROCESS
}

extern "C" void kernel_launch(void* const* d_in, const int* in_sizes, int n_in,
                              void* d_out, int out_size, void* d_ws, size_t ws_size,
                              hipStream_t stream) {
    const float* logits   = (const float*)d_in[0];
    const float* gumbel   = (const float*)d_in[1];
    const float* codebook = (const float*)d_in[2];

    const int tokens = in_sizes[0] / NUM_CODES;  // 8*4096 = 32768

    float* z_out = (float*)d_out;                               // [tokens, 256]
    float* y_out = (float*)d_out + (size_t)tokens * CODE_DIM;   // [tokens, 2048]

    int blocks = tokens < 2048 ? tokens : 2048;  // persistent grid-stride
    gumbel_codebook_kernel<<<blocks, BLOCK, 0, stream>>>(
        logits, gumbel, codebook, z_out, y_out, tokens);
}